// Round 10
// baseline (411.507 us; speedup 1.0000x reference)
//
#include <hip/hip_runtime.h>

#define NN 8192
#define DD 256
#define RT 32               // C rows per block
#define KC 128              // k-chunk
#define KS 4                // k-splits
#define KRANGE (NN / KS)    // 2048
#define NCH (KRANGE / KC)   // 16 chunks per block

typedef float v4f __attribute__((ext_vector_type(4)));
typedef short short8 __attribute__((ext_vector_type(8)));
typedef float f32x4 __attribute__((ext_vector_type(4)));
typedef unsigned short u16x4 __attribute__((ext_vector_type(4)));
typedef unsigned short u16x8 __attribute__((ext_vector_type(8)));

__device__ __forceinline__ unsigned short f2bf_rne(float x) {
    unsigned u = __float_as_uint(x);
    u += 0x7fffu + ((u >> 16) & 1u);
    return (unsigned short)(u >> 16);
}
__device__ __forceinline__ float bf_to_f(unsigned short b) {
    return __uint_as_float((unsigned)b << 16);
}

// scores[row] = dot(inputs[row,:], H_v)
__global__ __launch_bounds__(256) void scores_kernel(const float* __restrict__ inputs,
                                                     const float* __restrict__ Hv,
                                                     float* __restrict__ scores) {
    int wave = threadIdx.x >> 6;
    int lane = threadIdx.x & 63;
    int row  = blockIdx.x * 4 + wave;
    if (row >= NN) return;
    float4 v = ((const float4*)(inputs + (size_t)row * DD))[lane];
    float4 h = ((const float4*)Hv)[lane];
    float s = v.x * h.x + v.y * h.y + v.z * h.z + v.w * h.w;
    #pragma unroll
    for (int off = 32; off > 0; off >>= 1) s += __shfl_down(s, off, 64);
    if (lane == 0) scores[row] = s;
}

// B pre-packed in MFMA-fragment order:
// xtp[((t*256 + kc)*64 + lane)*8 + j] = bf16(inputs[k][n]),
//   n = t*16 + (lane&15), k = kc*32 + (lane>>4)*8 + j.
#define XP 258
__global__ __launch_bounds__(256) void xtp_kernel(const float* __restrict__ inputs,
                                                  unsigned short* __restrict__ xtp) {
    __shared__ unsigned short sx[64 * XP];     // [k-local][n]
    const int tid = threadIdx.x;
    const int k0  = blockIdx.x * 64;
    #pragma unroll
    for (int r = 0; r < 16; ++r) {
        int row = r * 4 + (tid >> 6);
        int col = (tid & 63) * 4;
        float4 v = *(const float4*)(inputs + (size_t)(k0 + row) * DD + col);
        u16x4 w;
        w[0] = f2bf_rne(v.x); w[1] = f2bf_rne(v.y); w[2] = f2bf_rne(v.z); w[3] = f2bf_rne(v.w);
        *(u16x4*)&sx[row * XP + col] = w;
    }
    __syncthreads();
    #pragma unroll
    for (int r = 0; r < 8; ++r) {
        int rid  = r * 256 + tid;
        int lane = rid & 63;
        int t    = (rid >> 6) & 15;
        int kcl  = rid >> 10;
        int n    = t * 16 + (lane & 15);
        int kl   = kcl * 32 + (lane >> 4) * 8;
        u16x8 w;
        #pragma unroll
        for (int j = 0; j < 8; ++j) w[j] = sx[(kl + j) * XP + n];
        size_t kcg = (size_t)(k0 >> 5) + kcl;
        *(u16x8*)(xtp + (((size_t)t * 256 + kcg) * 64 + lane) * 8) = w;
    }
}

// Dense-MFMA partial kernel, depth-2 adj prefetch, scores in LDS.
__global__ __launch_bounds__(512, 4) void spmm_kernel(const float* __restrict__ adj,
                                                      const unsigned short* __restrict__ xtp,
                                                      const float* __restrict__ scores,
                                                      float* __restrict__ pc,
                                                      float* __restrict__ pd) {
    __shared__ unsigned short sE[2][RT * KC];   // 2 x 8 KB, bank-swizzled
    __shared__ float sS[KRANGE];                // 8 KB

    const int tid  = threadIdx.x;
    const int lane = tid & 63;
    const int wave = tid >> 6;       // cols [wave*32, +32)
    const int q    = lane >> 4;
    const int m16  = lane & 15;

    const int ks    = blockIdx.x & (KS - 1);
    const int mb    = blockIdx.x >> 2;
    const int row0  = mb * RT;
    const int kbase = ks * KRANGE;

    // stage this K-range's scores once (one float4 per thread)
    ((float4*)sS)[tid] = ((const float4*)(scores + kbase))[tid];

    const int lrow = tid >> 4;           // E-gen row
    const int kgb  = tid & 15;           // 16-B k-block in chunk
    const int kg   = kgb * 8;
    const float* arow = adj + (size_t)(row0 + lrow) * NN + kbase;

    f32x4 acc[2][2] = {};
    float den = 0.f;

    // depth-2 rotating prefetch of the adj stream (nt: single-use)
    v4f pa[2][2];
    pa[0][0] = __builtin_nontemporal_load((const v4f*)(arow + kg));
    pa[0][1] = __builtin_nontemporal_load((const v4f*)(arow + kg + 4));
    pa[1][0] = __builtin_nontemporal_load((const v4f*)(arow + KC + kg));
    pa[1][1] = __builtin_nontemporal_load((const v4f*)(arow + KC + kg + 4));

    __syncthreads();   // sS ready

    for (int c = 0; c < NCH; ++c) {
        const int s = c & 1;

        // B-frags for chunk c — independent, issue first, consume after barrier.
        const size_t kcg0 = (size_t)((kbase + c * KC) >> 5);
        short8 bfr[2][4];
        #pragma unroll
        for (int nt = 0; nt < 2; ++nt) {
            const size_t t = (size_t)(wave * 2 + nt);
            #pragma unroll
            for (int kh = 0; kh < 4; ++kh)
                bfr[nt][kh] = *(const short8*)(xtp + ((t * 256 + kcg0 + kh) * 64 + lane) * 8);
        }

        // E-gen from slot s (loads issued 2 chunks ago) + LDS scores.
        float af[8] = { pa[s][0].x, pa[s][0].y, pa[s][0].z, pa[s][0].w,
                        pa[s][1].x, pa[s][1].y, pa[s][1].z, pa[s][1].w };
        u16x8 ev;
        #pragma unroll
        for (int i = 0; i < 8; ++i) {
            float a = af[i];
            float e = (a != 0.f) ? __expf(a * sS[c * KC + kg + i]) : 0.f;
            unsigned short b = f2bf_rne(e);
            ev[i] = b;
            den += bf_to_f(b);
        }

        // refill slot s with chunk c+2
        if (c + 2 < NCH) {
            pa[s][0] = __builtin_nontemporal_load((const v4f*)(arow + (c + 2) * KC + kg));
            pa[s][1] = __builtin_nontemporal_load((const v4f*)(arow + (c + 2) * KC + kg + 4));
        }

        *(u16x8*)&sE[s][lrow * KC + ((kgb ^ (lrow & 15)) * 8)] = ev;
        __syncthreads();

        // A-frags per-kh (small live set) + MFMAs.
        const unsigned short* Eb = sE[s];
        #pragma unroll
        for (int kh = 0; kh < 4; ++kh) {
            short8 a0 = *(const short8*)&Eb[m16 * KC + (((kh * 4 + q) ^ m16) * 8)];
            short8 a1 = *(const short8*)&Eb[(16 + m16) * KC + (((kh * 4 + q) ^ m16) * 8)];
            acc[0][0] = __builtin_amdgcn_mfma_f32_16x16x32_bf16(a0, bfr[0][kh], acc[0][0], 0, 0, 0);
            acc[0][1] = __builtin_amdgcn_mfma_f32_16x16x32_bf16(a0, bfr[1][kh], acc[0][1], 0, 0, 0);
            acc[1][0] = __builtin_amdgcn_mfma_f32_16x16x32_bf16(a1, bfr[0][kh], acc[1][0], 0, 0, 0);
            acc[1][1] = __builtin_amdgcn_mfma_f32_16x16x32_bf16(a1, bfr[1][kh], acc[1][1], 0, 0, 0);
        }
    }

    // partial denominator: reduce over 16 threads sharing lrow
    #pragma unroll
    for (int d = 1; d < 16; d <<= 1) den += __shfl_xor(den, d, 64);
    if ((tid & 15) == 0) pd[(size_t)ks * NN + row0 + lrow] = den;

    // partial C: C/D layout col=lane&15, row=q*4+reg
    float* pcb = pc + ((size_t)ks * NN + row0) * DD;
    #pragma unroll
    for (int mt = 0; mt < 2; ++mt)
        #pragma unroll
        for (int nt = 0; nt < 2; ++nt)
            #pragma unroll
            for (int r = 0; r < 4; ++r) {
                int rr = mt * 16 + q * 4 + r;
                pcb[(size_t)rr * DD + wave * 32 + nt * 16 + m16] = acc[mt][nt][r];
            }
}

// Combine K-split partials: out = sum(P) / sum(d)
__global__ __launch_bounds__(256) void reduce_kernel(const float* __restrict__ pc,
                                                     const float* __restrict__ pd,
                                                     float* __restrict__ out) {
    const int row = blockIdx.x;
    const int tid = threadIdx.x;
    float d = 0.f, v = 0.f;
    #pragma unroll
    for (int ks = 0; ks < KS; ++ks) {
        d += pd[(size_t)ks * NN + row];
        v += pc[((size_t)ks * NN + row) * DD + tid];
    }
    out[(size_t)row * DD + tid] = (d > 0.f) ? v / d : 0.f;
}

// ws-too-small fallback (needs only 32 KB scores).
__global__ __launch_bounds__(256) void attn_fallback(const float* __restrict__ adj,
                                                     const float* __restrict__ inputs,
                                                     const float* __restrict__ scores,
                                                     float* __restrict__ out) {
    __shared__ int   s_j[1024];
    __shared__ float s_e[1024];
    __shared__ int   s_cnt;
    const int row = blockIdx.x;
    const int tid = threadIdx.x;
    const float* arow = adj + (size_t)row * NN;
    float acc = 0.f, ssum = 0.f;
    for (int base = 0; base < NN; base += 1024) {
        if (tid == 0) s_cnt = 0;
        __syncthreads();
        float4 a = ((const float4*)(arow + base))[tid];
        int j0 = base + tid * 4;
        if (a.x != 0.f) { int k = atomicAdd(&s_cnt, 1); s_j[k] = j0 + 0; s_e[k] = __expf(a.x * scores[j0 + 0]); }
        if (a.y != 0.f) { int k = atomicAdd(&s_cnt, 1); s_j[k] = j0 + 1; s_e[k] = __expf(a.y * scores[j0 + 1]); }
        if (a.z != 0.f) { int k = atomicAdd(&s_cnt, 1); s_j[k] = j0 + 2; s_e[k] = __expf(a.z * scores[j0 + 2]); }
        if (a.w != 0.f) { int k = atomicAdd(&s_cnt, 1); s_j[k] = j0 + 3; s_e[k] = __expf(a.w * scores[j0 + 3]); }
        __syncthreads();
        int c = s_cnt;
        for (int k = 0; k < c; ++k) {
            float e = s_e[k];
            acc  += e * inputs[(size_t)s_j[k] * DD + tid];
            ssum += e;
        }
        __syncthreads();
    }
    out[(size_t)row * DD + tid] = (ssum > 0.f) ? acc / ssum : 0.f;
}

extern "C" void kernel_launch(void* const* d_in, const int* in_sizes, int n_in,
                              void* d_out, int out_size, void* d_ws, size_t ws_size,
                              hipStream_t stream) {
    const float* inputs = (const float*)d_in[0];  // [N, D] fp32
    const float* adj    = (const float*)d_in[1];  // [N, N] fp32
    const float* Hv     = (const float*)d_in[2];  // [D, 1] fp32
    float* out = (float*)d_out;                   // [N, D] fp32

    char* ws = (char*)d_ws;
    float*          scores = (float*)ws;                                     // 32 KB
    unsigned short* xtp    = (unsigned short*)(ws + 32768);                  // 4 MB
    float*          pd     = (float*)(ws + 32768 + (size_t)NN * DD * 2);     // 128 KB
    float*          pc     = (float*)(ws + 32768 + (size_t)NN * DD * 2 + KS * NN * 4); // 32 MB

    const size_t need = 32768 + (size_t)NN * DD * 2 + (size_t)KS * NN * 4
                      + (size_t)KS * NN * DD * 4;

    scores_kernel<<<NN / 4, 256, 0, stream>>>(inputs, Hv, scores);
    if (ws_size >= need) {
        xtp_kernel<<<NN / 64, 256, 0, stream>>>(inputs, xtp);
        spmm_kernel<<<(NN / RT) * KS, 512, 0, stream>>>(adj, xtp, scores, pc, pd);
        reduce_kernel<<<NN, 256, 0, stream>>>(pc, pd, out);
    } else {
        attn_fallback<<<NN, 256, 0, stream>>>(adj, inputs, scores, out);
    }
}

// Round 11
// 409.503 us; speedup vs baseline: 1.0049x; 1.0049x over previous
//
#include <hip/hip_runtime.h>

#define NN 8192
#define DD 256
#define RT 64               // C rows per block
#define KC 128              // k-chunk
#define KS 4                // k-splits
#define KRANGE (NN / KS)    // 2048
#define NCH (KRANGE / KC)   // 16 chunks per block

typedef float v4f __attribute__((ext_vector_type(4)));
typedef short short8 __attribute__((ext_vector_type(8)));
typedef float f32x4 __attribute__((ext_vector_type(4)));
typedef unsigned short u16x4 __attribute__((ext_vector_type(4)));
typedef unsigned short u16x8 __attribute__((ext_vector_type(8)));

__device__ __forceinline__ unsigned short f2bf_rne(float x) {
    unsigned u = __float_as_uint(x);
    u += 0x7fffu + ((u >> 16) & 1u);
    return (unsigned short)(u >> 16);
}
__device__ __forceinline__ float bf_to_f(unsigned short b) {
    return __uint_as_float((unsigned)b << 16);
}

// scores[row] = dot(inputs[row,:], H_v)
__global__ __launch_bounds__(256) void scores_kernel(const float* __restrict__ inputs,
                                                     const float* __restrict__ Hv,
                                                     float* __restrict__ scores) {
    int wave = threadIdx.x >> 6;
    int lane = threadIdx.x & 63;
    int row  = blockIdx.x * 4 + wave;
    if (row >= NN) return;
    float4 v = ((const float4*)(inputs + (size_t)row * DD))[lane];
    float4 h = ((const float4*)Hv)[lane];
    float s = v.x * h.x + v.y * h.y + v.z * h.z + v.w * h.w;
    #pragma unroll
    for (int off = 32; off > 0; off >>= 1) s += __shfl_down(s, off, 64);
    if (lane == 0) scores[row] = s;
}

// B pre-packed in MFMA-fragment order:
// xtp[((t*256 + kc)*64 + lane)*8 + j] = bf16(inputs[k][n]),
//   n = t*16 + (lane&15), k = kc*32 + (lane>>4)*8 + j.
#define XP 258
__global__ __launch_bounds__(256) void xtp_kernel(const float* __restrict__ inputs,
                                                  unsigned short* __restrict__ xtp) {
    __shared__ unsigned short sx[64 * XP];     // [k-local][n]
    const int tid = threadIdx.x;
    const int k0  = blockIdx.x * 64;
    #pragma unroll
    for (int r = 0; r < 16; ++r) {
        int row = r * 4 + (tid >> 6);
        int col = (tid & 63) * 4;
        float4 v = *(const float4*)(inputs + (size_t)(k0 + row) * DD + col);
        u16x4 w;
        w[0] = f2bf_rne(v.x); w[1] = f2bf_rne(v.y); w[2] = f2bf_rne(v.z); w[3] = f2bf_rne(v.w);
        *(u16x4*)&sx[row * XP + col] = w;
    }
    __syncthreads();
    #pragma unroll
    for (int r = 0; r < 8; ++r) {
        int rid  = r * 256 + tid;
        int lane = rid & 63;
        int t    = (rid >> 6) & 15;
        int kcl  = rid >> 10;
        int n    = t * 16 + (lane & 15);
        int kl   = kcl * 32 + (lane >> 4) * 8;
        u16x8 w;
        #pragma unroll
        for (int j = 0; j < 8; ++j) w[j] = sx[(kl + j) * XP + n];
        size_t kcg = (size_t)(k0 >> 5) + kcl;
        *(u16x8*)(xtp + (((size_t)t * 256 + kcg) * 64 + lane) * 8) = w;
    }
}

// Dense-MFMA partial kernel: 64 rows x 256 cols per block, depth-1 prefetch.
// RT=64 halves the block-count and thus the total B-fragment cache traffic
// (per-chunk B-slice reload is amortized over 2x the rows).
__global__ __launch_bounds__(512, 4) void spmm_kernel(const float* __restrict__ adj,
                                                      const unsigned short* __restrict__ xtp,
                                                      const float* __restrict__ scores,
                                                      float* __restrict__ pc,
                                                      float* __restrict__ pd) {
    __shared__ unsigned short sE[2][RT * KC];   // 2 x 16 KB, bank-swizzled
    __shared__ float sS[KRANGE];                // 8 KB

    const int tid  = threadIdx.x;
    const int lane = tid & 63;
    const int wave = tid >> 6;       // cols [wave*32, +32)
    const int q    = lane >> 4;
    const int m16  = lane & 15;

    const int ks    = blockIdx.x & (KS - 1);
    const int mb    = blockIdx.x >> 2;
    const int row0  = mb * RT;
    const int kbase = ks * KRANGE;

    // stage this K-range's scores once (one float4 per thread)
    ((float4*)sS)[tid] = ((const float4*)(scores + kbase))[tid];

    const int lrow = tid >> 4;           // E-gen row (this thread also does lrow+32)
    const int kgb  = tid & 15;           // 16-B k-block in chunk
    const int kg   = kgb * 8;
    const float* ar0 = adj + (size_t)(row0 + lrow) * NN + kbase;
    const float* ar1 = ar0 + (size_t)32 * NN;

    f32x4 acc[4][2] = {};
    float den0 = 0.f, den1 = 0.f;

    v4f a[2][2];
    a[0][0] = __builtin_nontemporal_load((const v4f*)(ar0 + kg));
    a[0][1] = __builtin_nontemporal_load((const v4f*)(ar0 + kg + 4));
    a[1][0] = __builtin_nontemporal_load((const v4f*)(ar1 + kg));
    a[1][1] = __builtin_nontemporal_load((const v4f*)(ar1 + kg + 4));

    __syncthreads();   // sS ready

    for (int c = 0; c < NCH; ++c) {
        const int s = c & 1;
        const int cn = (c + 1 < NCH ? c + 1 : c) * KC;

        // next chunk's adj loads (depth-1)
        v4f na[2][2];
        na[0][0] = __builtin_nontemporal_load((const v4f*)(ar0 + cn + kg));
        na[0][1] = __builtin_nontemporal_load((const v4f*)(ar0 + cn + kg + 4));
        na[1][0] = __builtin_nontemporal_load((const v4f*)(ar1 + cn + kg));
        na[1][1] = __builtin_nontemporal_load((const v4f*)(ar1 + cn + kg + 4));

        // B-frags for chunk c (independent of barrier; issue early)
        const size_t kcg0 = (size_t)((kbase + c * KC) >> 5);
        short8 bfr[2][4];
        #pragma unroll
        for (int nt = 0; nt < 2; ++nt) {
            const size_t t = (size_t)(wave * 2 + nt);
            #pragma unroll
            for (int kh = 0; kh < 4; ++kh)
                bfr[nt][kh] = *(const short8*)(xtp + ((t * 256 + kcg0 + kh) * 64 + lane) * 8);
        }

        // E-gen for rows lrow and lrow+32  ((lrow+32)&15 == lrow&15 -> same swizzle)
        #pragma unroll
        for (int h = 0; h < 2; ++h) {
            float af[8] = { a[h][0].x, a[h][0].y, a[h][0].z, a[h][0].w,
                            a[h][1].x, a[h][1].y, a[h][1].z, a[h][1].w };
            u16x8 ev;
            float dl = 0.f;
            #pragma unroll
            for (int i = 0; i < 8; ++i) {
                float v = af[i];
                float e = (v != 0.f) ? __expf(v * sS[c * KC + kg + i]) : 0.f;
                unsigned short b = f2bf_rne(e);
                ev[i] = b;
                dl += bf_to_f(b);
            }
            if (h) den1 += dl; else den0 += dl;
            *(u16x8*)&sE[s][(lrow + 32 * h) * KC + ((kgb ^ (lrow & 15)) * 8)] = ev;
        }
        __syncthreads();

        // A-frags + MFMAs
        const unsigned short* Eb = sE[s];
        #pragma unroll
        for (int kh = 0; kh < 4; ++kh) {
            short8 A[4];
            #pragma unroll
            for (int mt = 0; mt < 4; ++mt)
                A[mt] = *(const short8*)&Eb[(mt * 16 + m16) * KC + (((kh * 4 + q) ^ m16) * 8)];
            #pragma unroll
            for (int mt = 0; mt < 4; ++mt) {
                acc[mt][0] = __builtin_amdgcn_mfma_f32_16x16x32_bf16(A[mt], bfr[0][kh], acc[mt][0], 0, 0, 0);
                acc[mt][1] = __builtin_amdgcn_mfma_f32_16x16x32_bf16(A[mt], bfr[1][kh], acc[mt][1], 0, 0, 0);
            }
        }

        a[0][0] = na[0][0]; a[0][1] = na[0][1];
        a[1][0] = na[1][0]; a[1][1] = na[1][1];
    }

    // partial denominators: reduce over the 16 threads sharing lrow
    #pragma unroll
    for (int d = 1; d < 16; d <<= 1) {
        den0 += __shfl_xor(den0, d, 64);
        den1 += __shfl_xor(den1, d, 64);
    }
    if ((tid & 15) == 0) {
        pd[(size_t)ks * NN + row0 + lrow]      = den0;
        pd[(size_t)ks * NN + row0 + lrow + 32] = den1;
    }

    // partial C: C/D layout col=lane&15, row=q*4+reg
    float* pcb = pc + ((size_t)ks * NN + row0) * DD;
    #pragma unroll
    for (int mt = 0; mt < 4; ++mt)
        #pragma unroll
        for (int nt = 0; nt < 2; ++nt)
            #pragma unroll
            for (int r = 0; r < 4; ++r) {
                int rr = mt * 16 + q * 4 + r;
                pcb[(size_t)rr * DD + wave * 32 + nt * 16 + m16] = acc[mt][nt][r];
            }
}

// Combine K-split partials: out = sum(P) / sum(d)
__global__ __launch_bounds__(256) void reduce_kernel(const float* __restrict__ pc,
                                                     const float* __restrict__ pd,
                                                     float* __restrict__ out) {
    const int row = blockIdx.x;
    const int tid = threadIdx.x;
    float d = 0.f, v = 0.f;
    #pragma unroll
    for (int ks = 0; ks < KS; ++ks) {
        d += pd[(size_t)ks * NN + row];
        v += pc[((size_t)ks * NN + row) * DD + tid];
    }
    out[(size_t)row * DD + tid] = (d > 0.f) ? v / d : 0.f;
}

// ws-too-small fallback (needs only 32 KB scores).
__global__ __launch_bounds__(256) void attn_fallback(const float* __restrict__ adj,
                                                     const float* __restrict__ inputs,
                                                     const float* __restrict__ scores,
                                                     float* __restrict__ out) {
    __shared__ int   s_j[1024];
    __shared__ float s_e[1024];
    __shared__ int   s_cnt;
    const int row = blockIdx.x;
    const int tid = threadIdx.x;
    const float* arow = adj + (size_t)row * NN;
    float acc = 0.f, ssum = 0.f;
    for (int base = 0; base < NN; base += 1024) {
        if (tid == 0) s_cnt = 0;
        __syncthreads();
        float4 a = ((const float4*)(arow + base))[tid];
        int j0 = base + tid * 4;
        if (a.x != 0.f) { int k = atomicAdd(&s_cnt, 1); s_j[k] = j0 + 0; s_e[k] = __expf(a.x * scores[j0 + 0]); }
        if (a.y != 0.f) { int k = atomicAdd(&s_cnt, 1); s_j[k] = j0 + 1; s_e[k] = __expf(a.y * scores[j0 + 1]); }
        if (a.z != 0.f) { int k = atomicAdd(&s_cnt, 1); s_j[k] = j0 + 2; s_e[k] = __expf(a.z * scores[j0 + 2]); }
        if (a.w != 0.f) { int k = atomicAdd(&s_cnt, 1); s_j[k] = j0 + 3; s_e[k] = __expf(a.w * scores[j0 + 3]); }
        __syncthreads();
        int c = s_cnt;
        for (int k = 0; k < c; ++k) {
            float e = s_e[k];
            acc  += e * inputs[(size_t)s_j[k] * DD + tid];
            ssum += e;
        }
        __syncthreads();
    }
    out[(size_t)row * DD + tid] = (ssum > 0.f) ? acc / ssum : 0.f;
}

extern "C" void kernel_launch(void* const* d_in, const int* in_sizes, int n_in,
                              void* d_out, int out_size, void* d_ws, size_t ws_size,
                              hipStream_t stream) {
    const float* inputs = (const float*)d_in[0];  // [N, D] fp32
    const float* adj    = (const float*)d_in[1];  // [N, N] fp32
    const float* Hv     = (const float*)d_in[2];  // [D, 1] fp32
    float* out = (float*)d_out;                   // [N, D] fp32

    char* ws = (char*)d_ws;
    float*          scores = (float*)ws;                                     // 32 KB
    unsigned short* xtp    = (unsigned short*)(ws + 32768);                  // 4 MB
    float*          pd     = (float*)(ws + 32768 + (size_t)NN * DD * 2);     // 128 KB
    float*          pc     = (float*)(ws + 32768 + (size_t)NN * DD * 2 + KS * NN * 4); // 32 MB

    const size_t need = 32768 + (size_t)NN * DD * 2 + (size_t)KS * NN * 4
                      + (size_t)KS * NN * DD * 4;

    scores_kernel<<<NN / 4, 256, 0, stream>>>(inputs, Hv, scores);
    if (ws_size >= need) {
        xtp_kernel<<<NN / 64, 256, 0, stream>>>(inputs, xtp);
        spmm_kernel<<<(NN / RT) * KS, 512, 0, stream>>>(adj, xtp, scores, pc, pd);
        reduce_kernel<<<NN, 256, 0, stream>>>(pc, pd, out);
    } else {
        attn_fallback<<<NN, 256, 0, stream>>>(adj, inputs, scores, out);
    }
}

// Round 12
// 398.059 us; speedup vs baseline: 1.0338x; 1.0287x over previous
//
#include <hip/hip_runtime.h>

#define NN 8192
#define DD 256
#define RT 32               // C rows per block
#define KC 128              // k-chunk
#define KS 2                // k-splits
#define KRANGE (NN / KS)    // 4096
#define NCH (KRANGE / KC)   // 32 chunks per block

typedef float v4f __attribute__((ext_vector_type(4)));
typedef short short8 __attribute__((ext_vector_type(8)));
typedef float f32x4 __attribute__((ext_vector_type(4)));
typedef unsigned short u16x4 __attribute__((ext_vector_type(4)));
typedef unsigned short u16x8 __attribute__((ext_vector_type(8)));

// s_waitcnt immediate: lgkmcnt(0), vmcnt=max(63), expcnt=max(7) ->
// waits ONLY on LDS ops; leaves global loads in flight across the barrier.
#define WAIT_LGKM0 0xC07F

__device__ __forceinline__ unsigned short f2bf_rne(float x) {
    unsigned u = __float_as_uint(x);
    u += 0x7fffu + ((u >> 16) & 1u);
    return (unsigned short)(u >> 16);
}
__device__ __forceinline__ float bf_to_f(unsigned short b) {
    return __uint_as_float((unsigned)b << 16);
}

// scores[row] = dot(inputs[row,:], H_v)
__global__ __launch_bounds__(256) void scores_kernel(const float* __restrict__ inputs,
                                                     const float* __restrict__ Hv,
                                                     float* __restrict__ scores) {
    int wave = threadIdx.x >> 6;
    int lane = threadIdx.x & 63;
    int row  = blockIdx.x * 4 + wave;
    if (row >= NN) return;
    float4 v = ((const float4*)(inputs + (size_t)row * DD))[lane];
    float4 h = ((const float4*)Hv)[lane];
    float s = v.x * h.x + v.y * h.y + v.z * h.z + v.w * h.w;
    #pragma unroll
    for (int off = 32; off > 0; off >>= 1) s += __shfl_down(s, off, 64);
    if (lane == 0) scores[row] = s;
}

// B pre-packed in MFMA-fragment order:
// xtp[((t*256 + kc)*64 + lane)*8 + j] = bf16(inputs[k][n]),
//   n = t*16 + (lane&15), k = kc*32 + (lane>>4)*8 + j.
#define XP 258
__global__ __launch_bounds__(256) void xtp_kernel(const float* __restrict__ inputs,
                                                  unsigned short* __restrict__ xtp) {
    __shared__ unsigned short sx[64 * XP];     // [k-local][n]
    const int tid = threadIdx.x;
    const int k0  = blockIdx.x * 64;
    #pragma unroll
    for (int r = 0; r < 16; ++r) {
        int row = r * 4 + (tid >> 6);
        int col = (tid & 63) * 4;
        float4 v = *(const float4*)(inputs + (size_t)(k0 + row) * DD + col);
        u16x4 w;
        w[0] = f2bf_rne(v.x); w[1] = f2bf_rne(v.y); w[2] = f2bf_rne(v.z); w[3] = f2bf_rne(v.w);
        *(u16x4*)&sx[row * XP + col] = w;
    }
    __syncthreads();
    #pragma unroll
    for (int r = 0; r < 8; ++r) {
        int rid  = r * 256 + tid;
        int lane = rid & 63;
        int t    = (rid >> 6) & 15;
        int kcl  = rid >> 10;
        int n    = t * 16 + (lane & 15);
        int kl   = kcl * 32 + (lane >> 4) * 8;
        u16x8 w;
        #pragma unroll
        for (int j = 0; j < 8; ++j) w[j] = sx[(kl + j) * XP + n];
        size_t kcg = (size_t)(k0 >> 5) + kcl;
        *(u16x8*)(xtp + (((size_t)t * 256 + kcg) * 64 + lane) * 8) = w;
    }
}

// Dense-MFMA partial kernel (R9 structure) with a RAW barrier in the K-loop:
// lgkmcnt(0)-only wait + s_barrier keeps the adj prefetch and B-frag loads
// in flight across the chunk boundary (HIP __syncthreads drains vmcnt(0),
// which serialized every chunk on a ~900-cycle HBM drain).
__global__ __launch_bounds__(512, 4) void spmm_kernel(const float* __restrict__ adj,
                                                      const unsigned short* __restrict__ xtp,
                                                      const float* __restrict__ scores,
                                                      float* __restrict__ pc,
                                                      float* __restrict__ pd) {
    __shared__ unsigned short sE[2][RT * KC];   // 2 x 8 KB, bank-swizzled
    const int tid  = threadIdx.x;
    const int lane = tid & 63;
    const int wave = tid >> 6;       // cols [wave*32, +32)
    const int q    = lane >> 4;
    const int m16  = lane & 15;

    const int ks    = blockIdx.x & (KS - 1);
    const int mb    = blockIdx.x >> 1;
    const int row0  = mb * RT;
    const int kbase = ks * KRANGE;

    const int lrow = tid >> 4;           // E-gen row
    const int kgb  = tid & 15;           // 16-B k-block in chunk
    const int kg   = kgb * 8;
    const float* arow = adj + (size_t)(row0 + lrow) * NN + kbase;

    f32x4 acc[2][2] = {};
    float den = 0.f;

    v4f a0 = __builtin_nontemporal_load((const v4f*)(arow + kg));
    v4f a1 = __builtin_nontemporal_load((const v4f*)(arow + kg + 4));
    float4 s0 = *(const float4*)(scores + kbase + kg);
    float4 s1 = *(const float4*)(scores + kbase + kg + 4);

    for (int c = 0; c < NCH; ++c) {
        const int cn = (c + 1 < NCH ? c + 1 : c) * KC;
        v4f na0 = __builtin_nontemporal_load((const v4f*)(arow + cn + kg));
        v4f na1 = __builtin_nontemporal_load((const v4f*)(arow + cn + kg + 4));
        float4 ns0 = *(const float4*)(scores + kbase + cn + kg);
        float4 ns1 = *(const float4*)(scores + kbase + cn + kg + 4);

        float af[8] = { a0.x, a0.y, a0.z, a0.w, a1.x, a1.y, a1.z, a1.w };
        float sf[8] = { s0.x, s0.y, s0.z, s0.w, s1.x, s1.y, s1.z, s1.w };
        u16x8 ev;
        #pragma unroll
        for (int i = 0; i < 8; ++i) {
            float e = (af[i] != 0.f) ? __expf(af[i] * sf[i]) : 0.f;
            unsigned short b = f2bf_rne(e);
            ev[i] = b;
            den += bf_to_f(b);
        }
        *(u16x8*)&sE[c & 1][lrow * KC + ((kgb ^ (lrow & 15)) * 8)] = ev;

        // B-frags for chunk c (issue before the barrier; stay in flight).
        const size_t kcg0 = (size_t)((kbase + c * KC) >> 5);
        short8 bfr[2][4];
        #pragma unroll
        for (int nt = 0; nt < 2; ++nt) {
            const size_t t = (size_t)(wave * 2 + nt);
            #pragma unroll
            for (int kh = 0; kh < 4; ++kh)
                bfr[nt][kh] = *(const short8*)(xtp + ((t * 256 + kcg0 + kh) * 64 + lane) * 8);
        }

        // RAW barrier: drain LDS ops only; global loads stay outstanding.
        __builtin_amdgcn_s_waitcnt(WAIT_LGKM0);
        __builtin_amdgcn_s_barrier();

        // A-frags from swizzled LDS + MFMAs.
        const unsigned short* Eb = sE[c & 1];
        #pragma unroll
        for (int kh = 0; kh < 4; ++kh) {
            short8 A0 = *(const short8*)&Eb[m16 * KC + (((kh * 4 + q) ^ m16) * 8)];
            short8 A1 = *(const short8*)&Eb[(16 + m16) * KC + (((kh * 4 + q) ^ m16) * 8)];
            acc[0][0] = __builtin_amdgcn_mfma_f32_16x16x32_bf16(A0, bfr[0][kh], acc[0][0], 0, 0, 0);
            acc[0][1] = __builtin_amdgcn_mfma_f32_16x16x32_bf16(A0, bfr[1][kh], acc[0][1], 0, 0, 0);
            acc[1][0] = __builtin_amdgcn_mfma_f32_16x16x32_bf16(A1, bfr[0][kh], acc[1][0], 0, 0, 0);
            acc[1][1] = __builtin_amdgcn_mfma_f32_16x16x32_bf16(A1, bfr[1][kh], acc[1][1], 0, 0, 0);
        }

        a0 = na0; a1 = na1; s0 = ns0; s1 = ns1;
    }

    // partial denominator: reduce over 16 threads sharing lrow
    #pragma unroll
    for (int d = 1; d < 16; d <<= 1) den += __shfl_xor(den, d, 64);
    if ((tid & 15) == 0) pd[(size_t)ks * NN + row0 + lrow] = den;

    // partial C: C/D layout col=lane&15, row=q*4+reg
    float* pcb = pc + ((size_t)ks * NN + row0) * DD;
    #pragma unroll
    for (int mt = 0; mt < 2; ++mt)
        #pragma unroll
        for (int nt = 0; nt < 2; ++nt)
            #pragma unroll
            for (int r = 0; r < 4; ++r) {
                int rr = mt * 16 + q * 4 + r;
                pcb[(size_t)rr * DD + wave * 32 + nt * 16 + m16] = acc[mt][nt][r];
            }
}

// Combine K-split partials: out = sum(P) / sum(d)
__global__ __launch_bounds__(256) void reduce_kernel(const float* __restrict__ pc,
                                                     const float* __restrict__ pd,
                                                     float* __restrict__ out) {
    const int row = blockIdx.x;
    const int tid = threadIdx.x;
    float d = 0.f, v = 0.f;
    #pragma unroll
    for (int ks = 0; ks < KS; ++ks) {
        d += pd[(size_t)ks * NN + row];
        v += pc[((size_t)ks * NN + row) * DD + tid];
    }
    out[(size_t)row * DD + tid] = (d > 0.f) ? v / d : 0.f;
}

// ws-too-small fallback (needs only 32 KB scores).
__global__ __launch_bounds__(256) void attn_fallback(const float* __restrict__ adj,
                                                     const float* __restrict__ inputs,
                                                     const float* __restrict__ scores,
                                                     float* __restrict__ out) {
    __shared__ int   s_j[1024];
    __shared__ float s_e[1024];
    __shared__ int   s_cnt;
    const int row = blockIdx.x;
    const int tid = threadIdx.x;
    const float* arow = adj + (size_t)row * NN;
    float acc = 0.f, ssum = 0.f;
    for (int base = 0; base < NN; base += 1024) {
        if (tid == 0) s_cnt = 0;
        __syncthreads();
        float4 a = ((const float4*)(arow + base))[tid];
        int j0 = base + tid * 4;
        if (a.x != 0.f) { int k = atomicAdd(&s_cnt, 1); s_j[k] = j0 + 0; s_e[k] = __expf(a.x * scores[j0 + 0]); }
        if (a.y != 0.f) { int k = atomicAdd(&s_cnt, 1); s_j[k] = j0 + 1; s_e[k] = __expf(a.y * scores[j0 + 1]); }
        if (a.z != 0.f) { int k = atomicAdd(&s_cnt, 1); s_j[k] = j0 + 2; s_e[k] = __expf(a.z * scores[j0 + 2]); }
        if (a.w != 0.f) { int k = atomicAdd(&s_cnt, 1); s_j[k] = j0 + 3; s_e[k] = __expf(a.w * scores[j0 + 3]); }
        __syncthreads();
        int c = s_cnt;
        for (int k = 0; k < c; ++k) {
            float e = s_e[k];
            acc  += e * inputs[(size_t)s_j[k] * DD + tid];
            ssum += e;
        }
        __syncthreads();
    }
    out[(size_t)row * DD + tid] = (ssum > 0.f) ? acc / ssum : 0.f;
}

extern "C" void kernel_launch(void* const* d_in, const int* in_sizes, int n_in,
                              void* d_out, int out_size, void* d_ws, size_t ws_size,
                              hipStream_t stream) {
    const float* inputs = (const float*)d_in[0];  // [N, D] fp32
    const float* adj    = (const float*)d_in[1];  // [N, N] fp32
    const float* Hv     = (const float*)d_in[2];  // [D, 1] fp32
    float* out = (float*)d_out;                   // [N, D] fp32

    char* ws = (char*)d_ws;
    float*          scores = (float*)ws;                                     // 32 KB
    unsigned short* xtp    = (unsigned short*)(ws + 32768);                  // 4 MB
    float*          pd     = (float*)(ws + 32768 + (size_t)NN * DD * 2);     // 64 KB
    float*          pc     = (float*)(ws + 32768 + (size_t)NN * DD * 2 + KS * NN * 4); // 16 MB

    const size_t need = 32768 + (size_t)NN * DD * 2 + (size_t)KS * NN * 4
                      + (size_t)KS * NN * DD * 4;

    scores_kernel<<<NN / 4, 256, 0, stream>>>(inputs, Hv, scores);
    if (ws_size >= need) {
        xtp_kernel<<<NN / 64, 256, 0, stream>>>(inputs, xtp);
        spmm_kernel<<<(NN / RT) * KS, 512, 0, stream>>>(adj, xtp, scores, pc, pd);
        reduce_kernel<<<NN, 256, 0, stream>>>(pc, pd, out);
    } else {
        attn_fallback<<<NN, 256, 0, stream>>>(adj, inputs, scores, out);
    }
}